// Round 24
// baseline (410.125 us; speedup 1.0000x reference)
//
#include <hip/hip_runtime.h>
#include <hip/hip_bf16.h>

// Problem constants
#define CIN_   26
#define HIN_   721
#define WIN_   1440
#define K_     9
#define HOUT_  360
#define KH_    9
#define KW_    9
#define COUT_  256
#define WOUT_  720

#define WT     16                 // w-tile per block (720/16 = 45 tiles)
#define XFP    40                 // xs row pitch in f32 (exactly 10 float4 -> DMA-linear)
#define CCH    7                  // c-chunk (4 rounds: 7,7,7,5); chunk rows = 63
#define CK     (CIN_ * K_)        // 234
#define NKS2   9                  // phase-2 k-steps (k' = c*10+m, padded 288)
#define ACCP2  296                // u16 pitch: 592 B rows (16B aligned)
#define NMT    (COUT_ / 16)       // 16 m-tiles
#define NXCD   8
#define HBAND  (HOUT_ / NXCD)     // 45 h-rows per XCD band

typedef short bf16x8 __attribute__((ext_vector_type(8)));
typedef float f32x4  __attribute__((ext_vector_type(4)));

// Fragment-ordered bf16 weight in k'-layout: [(mt*NKS2+ks)*64 + lane]*8 + j  (144 KB)
__device__ unsigned short g_whi[NMT * NKS2 * 64 * 8];
// Per-h psi A-fragments for phase 1: [(h*3 + ks)*64 + lane]*8 + e  (1.1 MB)
__device__ unsigned short g_pfrag[HOUT_ * 3 * 64 * 8];

__device__ __forceinline__ unsigned short f2bf_rne(float f) {
    union { float f; unsigned u; } v; v.f = f;
    unsigned u = v.u;
    unsigned r = (u + 0x7FFFu + ((u >> 16) & 1u)) >> 16;
    return (unsigned short)r;
}
__device__ __forceinline__ unsigned pack_bf2(float a, float b) {
    const __hip_bfloat162 bv = __float22bfloat162_rn(make_float2(a, b));
    return *reinterpret_cast<const unsigned*>(&bv);
}
// async global->LDS DMA, 16B per lane; LDS dest = uniform base + lane*16
__device__ __forceinline__ void gload_lds16(const float* g, float* l) {
    __builtin_amdgcn_global_load_lds(
        (const __attribute__((address_space(1))) void*)g,
        (__attribute__((address_space(3))) void*)l,
        16, 0, 0);
}

// A-operand layout for mfma_f32_16x16x32_bf16: row m = lane&15, k = ks*32 + (lane>>4)*8 + j
// k' decoding: c = k'/10, m = k'%10; m==9 or k'>=260 -> zero
__global__ void prep_weight_kernel(const float* __restrict__ weight) {
    const int bid  = blockIdx.x;        // 0..143  (mt*NKS2 + ks)
    const int mt   = bid / NKS2;
    const int ks   = bid % NKS2;
    const int lane = threadIdx.x;       // 0..63
    const int row  = mt * 16 + (lane & 15);
    const int k0   = ks * 32 + (lane >> 4) * 8;
    const int base = ((mt * NKS2 + ks) * 64 + lane) * 8;
    #pragma unroll
    for (int j = 0; j < 8; ++j) {
        const int kp = k0 + j;
        float w = 0.f;
        if (kp < 260) {
            const int c = kp / 10, m = kp % 10;
            if (m < 9) w = weight[row * CK + c * 9 + m];
        }
        g_whi[base + j] = f2bf_rne(w);
    }
}

// Phase-1 contraction ordering over the 81 (dh,dw) taps, padded to 96:
//   slot s in [0,72):  dh = s>>3, dw = s&7    (adjacent-dw pairs)
//   slot s in [72,81): dh = s-72, dw = 8      (the dw=8 singles)
//   slot s in [81,96): zero padding
__global__ void prep_psi_kernel(const float* __restrict__ psi) {
    const int h    = blockIdx.x;        // 0..359
    const int lane = threadIdx.x;       // 0..63
    const int m    = lane & 15;
    const int kg   = lane >> 4;
    #pragma unroll
    for (int ks = 0; ks < 3; ++ks) {
        const int base = ((h * 3 + ks) * 64 + lane) * 8;
        #pragma unroll
        for (int e = 0; e < 8; ++e) {
            const int s = ks * 32 + kg * 8 + e;
            float v = 0.f;
            if (m < 9) {
                if (s < 72)      v = psi[(m * HOUT_ + h) * 81 + (s >> 3) * 9 + (s & 7)];
                else if (s < 81) v = psi[(m * HOUT_ + h) * 81 + (s - 72) * 9 + 8];
            }
            g_pfrag[base + e] = f2bf_rne(v);
        }
    }
}

// barrier that does NOT drain vmcnt: flush own LDS writes, then raw s_barrier
#define LDS_BARRIER()                                      \
    do {                                                   \
        asm volatile("s_waitcnt lgkmcnt(0)" ::: "memory"); \
        __builtin_amdgcn_s_barrier();                      \
    } while (0)
#define VM_WAIT(N) asm volatile("s_waitcnt vmcnt(" #N ")" ::: "memory")

// ---------- shared phase-1 body (staging + stencil MFMA into acc_s) ----------
// Emits into acc_s; caller supplies LDS arrays. Used by both the full kernel
// and the phase-1-only ablation so they measure identical code.
#define PHASE1_BODY(XS_F, ACC_S)                                                     \
    /* zero acc k'-padding cols [260,288) */                                         \
    _Pragma("unroll")                                                                \
    for (int t = 0; t < 2; ++t) {                                                    \
        const int e = tid + t * 256;                                                 \
        if (e < 16 * 28) ACC_S[e / 28][260 + e % 28] = 0;                            \
    }                                                                                \
    bf16x8 afrag[3];                                                                 \
    _Pragma("unroll")                                                                \
    for (int ks = 0; ks < 3; ++ks)                                                   \
        afrag[ks] = *(const bf16x8*)&g_pfrag[((h * 3 + ks) * 64 + lane) * 8];        \
    VM_WAIT(0);                                                                      \
    const int c0 = 2 * w0 - 4;                                                       \
    ISSUE_DMA(0, 0, 62);                                                             \
    ISSUE_DMA(1, 1, 62);                                                             \
    VM_WAIT(3);                                                                      \
    LDS_BARRIER();                                                                   \
    _Pragma("unroll")                                                                \
    for (int rd = 0; rd < 4; ++rd) {                                                 \
        const int nc = (rd == 3) ? (CIN_ - 3 * CCH) : CCH;                           \
        const float* xsf = &XS_F[rd & 1][0];                                         \
        for (int cc = wid; cc < nc; cc += 4) {                                       \
            const int c = rd * CCH + cc;                                             \
            const float* rbase = xsf + (cc * 9) * XFP + 2 * n;                       \
            f32x4 C = {0.f, 0.f, 0.f, 0.f};                                          \
            _Pragma("unroll")                                                        \
            for (int ks = 0; ks < 3; ++ks) {                                         \
                union { bf16x8 v; unsigned d[4]; unsigned short u[8]; } bf;          \
                if (ks < 2 || kg == 0) {                                             \
                    const float* rp = rbase + (ks * 4 + kg) * XFP;                   \
                    _Pragma("unroll")                                                \
                    for (int t = 0; t < 4; ++t) {                                    \
                        const float2 v2 = *reinterpret_cast<const float2*>(rp + 2 * t); \
                        bf.d[t] = pack_bf2(v2.x, v2.y);                              \
                    }                                                                \
                } else if (kg == 1) {                                                \
                    _Pragma("unroll")                                                \
                    for (int e = 0; e < 8; ++e)                                      \
                        bf.u[e] = f2bf_rne(rbase[e * XFP + 8]);                      \
                } else if (kg == 2) {                                                \
                    bf.d[0] = bf.d[1] = bf.d[2] = bf.d[3] = 0;                       \
                    bf.u[0] = f2bf_rne(rbase[8 * XFP + 8]);                          \
                } else {                                                             \
                    bf.d[0] = bf.d[1] = bf.d[2] = bf.d[3] = 0;                       \
                }                                                                    \
                C = __builtin_amdgcn_mfma_f32_16x16x32_bf16(afrag[ks], bf.v, C, 0, 0, 0); \
            }                                                                        \
            if (kg < 2) {                                                            \
                unsigned* ap = reinterpret_cast<unsigned*>(&ACC_S[n][c * 10 + kg * 4]); \
                ap[0] = pack_bf2(C[0], C[1]);                                        \
                ap[1] = pack_bf2(C[2], C[3]);                                        \
            } else if (kg == 2) {                                                    \
                *reinterpret_cast<unsigned*>(&ACC_S[n][c * 10 + 8]) = pack_bf2(C[0], 0.f); \
            }                                                                        \
        }                                                                            \
        if (rd == 0) {                                                               \
            LDS_BARRIER();                                                           \
            ISSUE_DMA(2, 0, 62);                                                     \
            VM_WAIT(3);                                                              \
            LDS_BARRIER();                                                           \
        } else if (rd == 1) {                                                        \
            LDS_BARRIER();                                                           \
            ISSUE_DMA(3, 1, 44);                                                     \
            VM_WAIT(3);                                                              \
            LDS_BARRIER();                                                           \
        } else if (rd == 2) {                                                        \
            LDS_BARRIER();                                                           \
            VM_WAIT(0);                                                              \
            LDS_BARRIER();                                                           \
        }                                                                            \
    }                                                                                \
    LDS_BARRIER();

#define ISSUE_DMA_DEF(XS_F)                                                      \
    const int cb_unused = 0; (void)cb_unused;

#define ISSUE_DMA(RD, BUF, RMAX)                                                 \
    do {                                                                         \
        const int cb = (RD) * CCH;                                               \
        _Pragma("unroll")                                                        \
        for (int it = 0; it < 3; ++it) {                                         \
            const int g64 = wid + 4 * it;                                        \
            const int ii  = g64 * 64 + lane;                                     \
            int row = ii / 10;                                                   \
            const int q = ii - row * 10;                                         \
            if (row > (RMAX)) row = (RMAX);                                      \
            const int dh = row % 9;                                              \
            const int c  = cb + row / 9;                                         \
            int r = hib + dh;                                                    \
            if (r > HIN_ - 1) r = HIN_ - 1;                                      \
            int gc = c0 + 4 * q;                                                 \
            if (gc < 0)          gc += WIN_;                                     \
            else if (gc >= WIN_) gc -= WIN_;                                     \
            gload_lds16(x + ((size_t)c * HIN_ + r) * WIN_ + gc,                  \
                        &XS_LOCAL[BUF][g64 * 256]);                              \
        }                                                                        \
    } while (0)

// ---------------- full fused kernel (r23, unchanged semantics) ----------------
__global__ __launch_bounds__(256, 4)
void disco_fused_kernel(const float* __restrict__ x,
                        const int*   __restrict__ hi_base,
                        float* __restrict__ out)
{
    __shared__ float xs_f[2][12 * 256];
    __shared__ __align__(16) unsigned short acc_s[WT][ACCP2];

    const int b    = blockIdx.x;
    const int xcd  = b & (NXCD - 1);
    const int jb   = b >> 3;
    const int h    = xcd * HBAND + jb / 45;
    const int tile = jb % 45;
    const int w0   = tile * WT;
    const int tid  = threadIdx.x;
    const int hib  = hi_base[h];

    const int lane = tid & 63;
    const int wid  = tid >> 6;
    const int n    = lane & 15;
    const int kg   = lane >> 4;

    #define XS_LOCAL xs_f
    PHASE1_BODY(xs_f, acc_s)
    #undef XS_LOCAL

    // ---- phase 2: C[256x16] = W[256xK'] * acc[K'x16], weight software-pipelined ----
    f32x4 C0 = {0.f, 0.f, 0.f, 0.f};
    f32x4 C1 = C0, C2 = C0, C3 = C0;
    const unsigned short* wp = g_whi + ((size_t)(wid * 4) * NKS2 * 64 + lane) * 8;

    bf16x8 wc[4];
    #pragma unroll
    for (int i = 0; i < 4; ++i)
        wc[i] = *(const bf16x8*)(wp + (size_t)i * NKS2 * 512);

    #pragma unroll
    for (int ks = 0; ks < NKS2; ++ks) {
        bf16x8 wn[4];
        if (ks + 1 < NKS2) {
            #pragma unroll
            for (int i = 0; i < 4; ++i)
                wn[i] = *(const bf16x8*)(wp + ((size_t)i * NKS2 + (ks + 1)) * 512);
        }
        const bf16x8 bhi = *(const bf16x8*)&acc_s[n][ks * 32 + kg * 8];
        C0 = __builtin_amdgcn_mfma_f32_16x16x32_bf16(wc[0], bhi, C0, 0, 0, 0);
        C1 = __builtin_amdgcn_mfma_f32_16x16x32_bf16(wc[1], bhi, C1, 0, 0, 0);
        C2 = __builtin_amdgcn_mfma_f32_16x16x32_bf16(wc[2], bhi, C2, 0, 0, 0);
        C3 = __builtin_amdgcn_mfma_f32_16x16x32_bf16(wc[3], bhi, C3, 0, 0, 0);
        if (ks + 1 < NKS2) {
            #pragma unroll
            for (int i = 0; i < 4; ++i) wc[i] = wn[i];
        }
    }

    #pragma unroll
    for (int i = 0; i < 4; ++i) {
        const f32x4 acc = (i == 0) ? C0 : (i == 1) ? C1 : (i == 2) ? C2 : C3;
        const int m0 = (wid * 4 + i) * 16 + kg * 4;
        #pragma unroll
        for (int r = 0; r < 4; ++r) {
            out[(size_t)(m0 + r) * (HOUT_ * WOUT_) + h * WOUT_ + w0 + n] = acc[r];
        }
    }
}

// ---------------- ABLATION: phase-1 only, grid 2x16200, no global writes ----------------
__global__ __launch_bounds__(256, 4)
void abl_p1_kernel(const float* __restrict__ x,
                   const int*   __restrict__ hi_base)
{
    __shared__ float xs_f[2][12 * 256];
    __shared__ __align__(16) unsigned short acc_s[WT][ACCP2];

    int b = blockIdx.x;                 // 0..32399 -> same work twice
    if (b >= 16200) b -= 16200;
    const int xcd  = b & (NXCD - 1);
    const int jb   = b >> 3;
    const int h    = xcd * HBAND + jb / 45;
    const int tile = jb % 45;
    const int w0   = tile * WT;
    const int tid  = threadIdx.x;
    const int hib  = hi_base[h];

    const int lane = tid & 63;
    const int wid  = tid >> 6;
    const int n    = lane & 15;
    const int kg   = lane >> 4;

    #define XS_LOCAL xs_f
    PHASE1_BODY(xs_f, acc_s)
    #undef XS_LOCAL

    // keep acc_s (and thus the whole phase-1 chain) live without global traffic
    unsigned keep = 0;
    #pragma unroll
    for (int t = 0; t < 8; ++t)
        keep ^= reinterpret_cast<const unsigned*>(&acc_s[0][0])[(tid + t * 256) % (WT * ACCP2 / 2)];
    asm volatile("" :: "v"(keep));
}

extern "C" void kernel_launch(void* const* d_in, const int* in_sizes, int n_in,
                              void* d_out, int out_size, void* d_ws, size_t ws_size,
                              hipStream_t stream)
{
    const float* x       = (const float*)d_in[0];
    const float* psi     = (const float*)d_in[1];
    const float* weight  = (const float*)d_in[2];
    const int*   hi_base = (const int*)d_in[3];
    float* out = (float*)d_out;

    hipLaunchKernelGGL(prep_weight_kernel, dim3(NMT * NKS2), dim3(64), 0, stream, weight);
    hipLaunchKernelGGL(prep_psi_kernel,    dim3(HOUT_),      dim3(64), 0, stream, psi);

    // ABLATION dispatch (2x grid so it tops the rocprof table): phase-1 only
    hipLaunchKernelGGL(abl_p1_kernel, dim3(2 * 45 * HOUT_), dim3(256), 0, stream,
                       x, hi_base);

    // real kernel (correct output)
    hipLaunchKernelGGL(disco_fused_kernel, dim3(45 * HOUT_), dim3(256), 0, stream,
                       x, hi_base, out);
}

// Round 25
// 380.338 us; speedup vs baseline: 1.0783x; 1.0783x over previous
//
#include <hip/hip_runtime.h>
#include <hip/hip_bf16.h>

// Problem constants
#define CIN_   26
#define HIN_   721
#define WIN_   1440
#define K_     9
#define HOUT_  360
#define KH_    9
#define KW_    9
#define COUT_  256
#define WOUT_  720

#define WT     16                 // w-tile width (720/16 = 45 tiles per h)
#define XFP    40                 // xs row pitch in f32 (10 float4 -> DMA-linear)
#define CCH    7                  // c-chunk (4 rounds: 7,7,7,5)
#define CK     (CIN_ * K_)        // 234
#define NKS2   9                  // phase-2 k-steps (k' = c*10+m, padded 288)
#define ACCP2  296                // u16 pitch: 592 B rows (16B aligned)
#define NMT    (COUT_ / 16)       // 16 m-tiles
#define NXCD   8
#define TPB    5                  // tiles per block (45 = 9 groups * 5)

typedef short bf16x8 __attribute__((ext_vector_type(8)));
typedef float f32x4  __attribute__((ext_vector_type(4)));

// Fragment-ordered bf16 weight in k'-layout: [(mt*NKS2+ks)*64 + lane]*8 + j  (144 KB)
__device__ unsigned short g_whi[NMT * NKS2 * 64 * 8];
// Per-h psi A-fragments for phase 1: [(h*3 + ks)*64 + lane]*8 + e  (1.1 MB)
__device__ unsigned short g_pfrag[HOUT_ * 3 * 64 * 8];

__device__ __forceinline__ unsigned short f2bf_rne(float f) {
    union { float f; unsigned u; } v; v.f = f;
    unsigned u = v.u;
    unsigned r = (u + 0x7FFFu + ((u >> 16) & 1u)) >> 16;
    return (unsigned short)r;
}
__device__ __forceinline__ unsigned pack_bf2(float a, float b) {
    const __hip_bfloat162 bv = __float22bfloat162_rn(make_float2(a, b));
    return *reinterpret_cast<const unsigned*>(&bv);
}
// async global->LDS DMA, 16B per lane; LDS dest = uniform base + lane*16
__device__ __forceinline__ void gload_lds16(const float* g, float* l) {
    __builtin_amdgcn_global_load_lds(
        (const __attribute__((address_space(1))) void*)g,
        (__attribute__((address_space(3))) void*)l,
        16, 0, 0);
}

// A-operand layout for mfma_f32_16x16x32_bf16: row m = lane&15, k = ks*32 + (lane>>4)*8 + j
// k' decoding: c = k'/10, m = k'%10; m==9 or k'>=260 -> zero
__global__ void prep_weight_kernel(const float* __restrict__ weight) {
    const int bid  = blockIdx.x;        // 0..143  (mt*NKS2 + ks)
    const int mt   = bid / NKS2;
    const int ks   = bid % NKS2;
    const int lane = threadIdx.x;       // 0..63
    const int row  = mt * 16 + (lane & 15);
    const int k0   = ks * 32 + (lane >> 4) * 8;
    const int base = ((mt * NKS2 + ks) * 64 + lane) * 8;
    #pragma unroll
    for (int j = 0; j < 8; ++j) {
        const int kp = k0 + j;
        float w = 0.f;
        if (kp < 260) {
            const int c = kp / 10, m = kp % 10;
            if (m < 9) w = weight[row * CK + c * 9 + m];
        }
        g_whi[base + j] = f2bf_rne(w);
    }
}

// Phase-1 contraction ordering over the 81 (dh,dw) taps, padded to 96:
//   slot s in [0,72):  dh = s>>3, dw = s&7    (adjacent-dw pairs)
//   slot s in [72,81): dh = s-72, dw = 8      (the dw=8 singles)
//   slot s in [81,96): zero padding
__global__ void prep_psi_kernel(const float* __restrict__ psi) {
    const int h    = blockIdx.x;        // 0..359
    const int lane = threadIdx.x;       // 0..63
    const int m    = lane & 15;
    const int kg   = lane >> 4;
    #pragma unroll
    for (int ks = 0; ks < 3; ++ks) {
        const int base = ((h * 3 + ks) * 64 + lane) * 8;
        #pragma unroll
        for (int e = 0; e < 8; ++e) {
            const int s = ks * 32 + kg * 8 + e;
            float v = 0.f;
            if (m < 9) {
                if (s < 72)      v = psi[(m * HOUT_ + h) * 81 + (s >> 3) * 9 + (s & 7)];
                else if (s < 81) v = psi[(m * HOUT_ + h) * 81 + (s - 72) * 9 + 8];
            }
            g_pfrag[base + e] = f2bf_rne(v);
        }
    }
}

// barrier that does NOT drain vmcnt: flush own LDS writes, then raw s_barrier
#define LDS_BARRIER()                                      \
    do {                                                   \
        asm volatile("s_waitcnt lgkmcnt(0)" ::: "memory"); \
        __builtin_amdgcn_s_barrier();                      \
    } while (0)
#define VM_WAIT(N) asm volatile("s_waitcnt vmcnt(" #N ")" ::: "memory")

// issue one chunk's 9 DMA loads (3 per wave). C0V = tile base col.
#define ISSUE(C0V, RD, BUF, RMAX)                                                \
do {                                                                             \
    const int cb = (RD) * CCH;                                                   \
    _Pragma("unroll")                                                            \
    for (int it = 0; it < 3; ++it) {                                             \
        const int g64 = wid + 4 * it;                                            \
        const int ii  = g64 * 64 + lane;                                         \
        int row = ii / 10;                                                       \
        const int q = ii - row * 10;                                             \
        if (row > (RMAX)) row = (RMAX);                                          \
        const int dh = row % 9;                                                  \
        const int c  = cb + row / 9;                                             \
        int r = hib + dh;                                                        \
        if (r > HIN_ - 1) r = HIN_ - 1;                                          \
        int gc = (C0V) + 4 * q;                                                  \
        if (gc < 0)          gc += WIN_;                                         \
        else if (gc >= WIN_) gc -= WIN_;                                         \
        gload_lds16(x + ((size_t)c * HIN_ + r) * WIN_ + gc,                      \
                    &xs_f[BUF][g64 * 256]);                                      \
    }                                                                            \
} while (0)

// one phase-1 round: fragment build from xs_f[BUF] + stencil MFMA into ACC
#define P1_ROUND(RD, BUF, ACC)                                                   \
do {                                                                             \
    const int nc = ((RD) == 3) ? (CIN_ - 3 * CCH) : CCH;                         \
    const float* xsf = &xs_f[BUF][0];                                            \
    for (int cc = wid; cc < nc; cc += 4) {                                       \
        const int c = (RD) * CCH + cc;                                           \
        const float* rbase = xsf + (cc * 9) * XFP + 2 * n;                       \
        f32x4 C = {0.f, 0.f, 0.f, 0.f};                                          \
        _Pragma("unroll")                                                        \
        for (int ks = 0; ks < 3; ++ks) {                                         \
            union { bf16x8 v; unsigned d[4]; unsigned short u[8]; } bf;          \
            if (ks < 2 || kg == 0) {                                             \
                const float* rp = rbase + (ks * 4 + kg) * XFP;                   \
                _Pragma("unroll")                                                \
                for (int t2 = 0; t2 < 4; ++t2) {                                 \
                    const float2 v2 = *reinterpret_cast<const float2*>(rp + 2 * t2); \
                    bf.d[t2] = pack_bf2(v2.x, v2.y);                             \
                }                                                                \
            } else if (kg == 1) {                                                \
                _Pragma("unroll")                                                \
                for (int e = 0; e < 8; ++e)                                      \
                    bf.u[e] = f2bf_rne(rbase[e * XFP + 8]);                      \
            } else if (kg == 2) {                                                \
                bf.d[0] = bf.d[1] = bf.d[2] = bf.d[3] = 0;                       \
                bf.u[0] = f2bf_rne(rbase[8 * XFP + 8]);                          \
            } else {                                                             \
                bf.d[0] = bf.d[1] = bf.d[2] = bf.d[3] = 0;                       \
            }                                                                    \
            C = __builtin_amdgcn_mfma_f32_16x16x32_bf16(afrag[ks], bf.v, C, 0, 0, 0); \
        }                                                                        \
        if (kg < 2) {                                                            \
            unsigned* ap = reinterpret_cast<unsigned*>(&ACC[n][c * 10 + kg * 4]);\
            ap[0] = pack_bf2(C[0], C[1]);                                        \
            ap[1] = pack_bf2(C[2], C[3]);                                        \
        } else if (kg == 2) {                                                    \
            *reinterpret_cast<unsigned*>(&ACC[n][c * 10 + 8]) = pack_bf2(C[0], 0.f); \
        }                                                                        \
    }                                                                            \
} while (0)

// phase-2 GEMM + store for block-local tile TT (reads acc_s[TT&1])
#define P2_STORE(TT)                                                             \
do {                                                                             \
    const unsigned short (*accp)[ACCP2] =                                        \
        (const unsigned short (*)[ACCP2])acc_s[(TT) & 1];                        \
    f32x4 C0 = {0.f, 0.f, 0.f, 0.f}, C1 = C0, C2 = C0, C3 = C0;                  \
    bf16x8 wc[4];                                                                \
    _Pragma("unroll")                                                            \
    for (int i = 0; i < 4; ++i)                                                  \
        wc[i] = *(const bf16x8*)(wp + (size_t)i * NKS2 * 512);                   \
    _Pragma("unroll")                                                            \
    for (int ks = 0; ks < NKS2; ++ks) {                                          \
        bf16x8 wn[4];                                                            \
        if (ks + 1 < NKS2) {                                                     \
            _Pragma("unroll")                                                    \
            for (int i = 0; i < 4; ++i)                                          \
                wn[i] = *(const bf16x8*)(wp + ((size_t)i * NKS2 + (ks + 1)) * 512); \
        }                                                                        \
        const bf16x8 bhi = *(const bf16x8*)&accp[n][ks * 32 + kg * 8];           \
        C0 = __builtin_amdgcn_mfma_f32_16x16x32_bf16(wc[0], bhi, C0, 0, 0, 0);   \
        C1 = __builtin_amdgcn_mfma_f32_16x16x32_bf16(wc[1], bhi, C1, 0, 0, 0);   \
        C2 = __builtin_amdgcn_mfma_f32_16x16x32_bf16(wc[2], bhi, C2, 0, 0, 0);   \
        C3 = __builtin_amdgcn_mfma_f32_16x16x32_bf16(wc[3], bhi, C3, 0, 0, 0);   \
        if (ks + 1 < NKS2) {                                                     \
            _Pragma("unroll")                                                    \
            for (int i = 0; i < 4; ++i) wc[i] = wn[i];                           \
        }                                                                        \
    }                                                                            \
    const int w0s = (tile0 + (TT)) * WT;                                         \
    _Pragma("unroll")                                                            \
    for (int i = 0; i < 4; ++i) {                                                \
        const f32x4 a2 = (i == 0) ? C0 : (i == 1) ? C1 : (i == 2) ? C2 : C3;     \
        const int m0 = (wid * 4 + i) * 16 + kg * 4;                              \
        _Pragma("unroll")                                                        \
        for (int r = 0; r < 4; ++r)                                              \
            out[(size_t)(m0 + r) * (HOUT_ * WOUT_) + h * WOUT_ + w0s + n] = a2[r]; \
    }                                                                            \
} while (0)

__global__ __launch_bounds__(256, 3)
void disco_fused_kernel(const float* __restrict__ x,
                        const int*   __restrict__ hi_base,
                        float* __restrict__ out)
{
    __shared__ float xs_f[2][12 * 256];                           // 24576 B
    __shared__ __align__(16) unsigned short acc_s[2][WT][ACCP2];  // 18944 B (total 43520 -> 3/CU)

    // grid 3240 = 8 XCDs * 405; per XCD: 45 h * 9 groups of TPB=5 tiles
    const int b     = blockIdx.x;
    const int xcd   = b & (NXCD - 1);
    const int j     = b >> 3;            // 0..404
    const int h     = xcd * 45 + j / 9;
    const int tile0 = (j % 9) * TPB;
    const int tid   = threadIdx.x;

    const int hib = hi_base[h];          // in [0, 716]

    const int lane = tid & 63;
    const int wid  = tid >> 6;           // 4 waves
    const int n    = lane & 15;
    const int kg   = lane >> 4;

    // ---- zero both acc buffers' k'-padding cols [260,288) ----
    for (int e = tid; e < 2 * 16 * 28; e += 256)
        acc_s[e / 448][(e % 448) / 28][260 + (e % 28)] = 0;

    // ---- hoisted per-block state: psi A-fragments (h fixed), weight base ----
    bf16x8 afrag[3];
    #pragma unroll
    for (int ks = 0; ks < 3; ++ks)
        afrag[ks] = *(const bf16x8*)&g_pfrag[((h * 3 + ks) * 64 + lane) * 8];
    const unsigned short* wp = g_whi + ((size_t)(wid * 4) * NKS2 * 64 + lane) * 8;
    VM_WAIT(0);     // drain; vmcnt now counts only DMA/stores below

    // ---- tile loop: p2(t-1) interleaved between rd2(t) and rd3(t) ----
    for (int t = 0; t < TPB; ++t) {
        const int c0  = 2 * (tile0 + t) * WT - 4;
        const int c0n = 2 * (tile0 + t + 1) * WT - 4;
        unsigned short (*acc)[ACCP2] = acc_s[t & 1];

        if (t == 0) {
            ISSUE(c0, 0, 0, 62);         // chunk0 -> buf0
            ISSUE(c0, 1, 1, 62);         // chunk1 -> buf1
            VM_WAIT(3);                  // chunk0 landed
            LDS_BARRIER();
        }

        P1_ROUND(0, 0, acc);
        LDS_BARRIER();                   // all waves done reading buf0
        ISSUE(c0, 2, 0, 62);             // chunk2 -> buf0
        VM_WAIT(3);                      // chunk1 landed (chunk2 flying)
        LDS_BARRIER();

        P1_ROUND(1, 1, acc);
        LDS_BARRIER();
        ISSUE(c0, 3, 1, 44);             // chunk3 -> buf1
        VM_WAIT(3);                      // chunk2 landed
        LDS_BARRIER();

        P1_ROUND(2, 0, acc);
        LDS_BARRIER();
        if (t + 1 < TPB) {
            ISSUE(c0n, 0, 0, 62);        // next-tile chunk0 -> buf0 (flies under p2)
            VM_WAIT(3);                  // chunk3 landed
        } else {
            VM_WAIT(0);                  // no prefetch cover: drain chunk3
        }
        LDS_BARRIER();

        if (t > 0) P2_STORE(t - 1);      // phase-2 sandwiched inside phase-1

        P1_ROUND(3, 1, acc);
        LDS_BARRIER();
        if (t + 1 < TPB) {
            ISSUE(c0n, 1, 1, 62);        // next-tile chunk1 -> buf1
            VM_WAIT(3);                  // next chunk0 landed (+ stores drained)
        } else {
            VM_WAIT(0);
        }
        LDS_BARRIER();
    }
    P2_STORE(TPB - 1);                   // epilogue: last tile's phase-2
}

extern "C" void kernel_launch(void* const* d_in, const int* in_sizes, int n_in,
                              void* d_out, int out_size, void* d_ws, size_t ws_size,
                              hipStream_t stream)
{
    const float* x       = (const float*)d_in[0];
    const float* psi     = (const float*)d_in[1];
    const float* weight  = (const float*)d_in[2];
    const int*   hi_base = (const int*)d_in[3];
    float* out = (float*)d_out;

    hipLaunchKernelGGL(prep_weight_kernel, dim3(NMT * NKS2), dim3(64), 0, stream, weight);
    hipLaunchKernelGGL(prep_psi_kernel,    dim3(HOUT_),      dim3(64), 0, stream, psi);

    hipLaunchKernelGGL(disco_fused_kernel, dim3(3240), dim3(256), 0, stream,
                       x, hi_base, out);
}

// Round 26
// 255.053 us; speedup vs baseline: 1.6080x; 1.4912x over previous
//
#include <hip/hip_runtime.h>
#include <hip/hip_bf16.h>

// Problem constants
#define CIN_   26
#define HIN_   721
#define WIN_   1440
#define K_     9
#define HOUT_  360
#define KH_    9
#define KW_    9
#define COUT_  256
#define WOUT_  720

#define WT     16                 // w-tile per block (720/16 = 45 tiles)
#define XFP    40                 // xs row pitch in f32 (exactly 10 float4 -> DMA-linear)
#define CCH    7                  // c-chunk (4 rounds: 7,7,7,5); chunk rows = 63
#define CK     (CIN_ * K_)        // 234
#define NKS2   9                  // phase-2 k-steps (k' = c*10+m, padded 288)
#define ACCP2  296                // u16 pitch: 592 B rows (16B aligned)
#define NMT    (COUT_ / 16)       // 16 m-tiles
#define NXCD   8
#define HBAND  (HOUT_ / NXCD)     // 45 h-rows per XCD band

typedef short bf16x8 __attribute__((ext_vector_type(8)));
typedef float f32x4  __attribute__((ext_vector_type(4)));

// Fragment-ordered bf16 weight in k'-layout: [(mt*NKS2+ks)*64 + lane]*8 + j  (144 KB)
__device__ unsigned short g_whi[NMT * NKS2 * 64 * 8];
// Per-h psi A-fragments for phase 1: [(h*3 + ks)*64 + lane]*8 + e  (1.1 MB)
__device__ unsigned short g_pfrag[HOUT_ * 3 * 64 * 8];

__device__ __forceinline__ unsigned short f2bf_rne(float f) {
    union { float f; unsigned u; } v; v.f = f;
    unsigned u = v.u;
    unsigned r = (u + 0x7FFFu + ((u >> 16) & 1u)) >> 16;
    return (unsigned short)r;
}
__device__ __forceinline__ unsigned pack_bf2(float a, float b) {
    const __hip_bfloat162 bv = __float22bfloat162_rn(make_float2(a, b));
    return *reinterpret_cast<const unsigned*>(&bv);
}
// async global->LDS DMA, 16B per lane; LDS dest = uniform base + lane*16
__device__ __forceinline__ void gload_lds16(const float* g, float* l) {
    __builtin_amdgcn_global_load_lds(
        (const __attribute__((address_space(1))) void*)g,
        (__attribute__((address_space(3))) void*)l,
        16, 0, 0);
}

// ---- merged prep: blocks [0,144) pack weight fragments, [144,504) pack psi ----
// weight A-layout: row m = lane&15, k = ks*32 + (lane>>4)*8 + j
// k' decoding: c = k'/10, m = k'%10; m==9 or k'>=260 -> zero
// psi slot ordering: s<72: dh=s>>3, dw=s&7; 72<=s<81: dh=s-72, dw=8; s>=81: zero
__global__ void prep_kernel(const float* __restrict__ weight,
                            const float* __restrict__ psi) {
    const int lane = threadIdx.x;       // 0..63
    if (blockIdx.x < NMT * NKS2) {
        const int bid  = blockIdx.x;    // 0..143  (mt*NKS2 + ks)
        const int mt   = bid / NKS2;
        const int ks   = bid % NKS2;
        const int row  = mt * 16 + (lane & 15);
        const int k0   = ks * 32 + (lane >> 4) * 8;
        const int base = ((mt * NKS2 + ks) * 64 + lane) * 8;
        #pragma unroll
        for (int j = 0; j < 8; ++j) {
            const int kp = k0 + j;
            float w = 0.f;
            if (kp < 260) {
                const int c = kp / 10, m = kp % 10;
                if (m < 9) w = weight[row * CK + c * 9 + m];
            }
            g_whi[base + j] = f2bf_rne(w);
        }
    } else {
        const int h  = blockIdx.x - NMT * NKS2;   // 0..359
        const int m  = lane & 15;
        const int kg = lane >> 4;
        #pragma unroll
        for (int ks = 0; ks < 3; ++ks) {
            const int base = ((h * 3 + ks) * 64 + lane) * 8;
            #pragma unroll
            for (int e = 0; e < 8; ++e) {
                const int s = ks * 32 + kg * 8 + e;
                float v = 0.f;
                if (m < 9) {
                    if (s < 72)      v = psi[(m * HOUT_ + h) * 81 + (s >> 3) * 9 + (s & 7)];
                    else if (s < 81) v = psi[(m * HOUT_ + h) * 81 + (s - 72) * 9 + 8];
                }
                g_pfrag[base + e] = f2bf_rne(v);
            }
        }
    }
}

// barrier that does NOT drain vmcnt: flush own LDS writes, then raw s_barrier
#define LDS_BARRIER()                                      \
    do {                                                   \
        asm volatile("s_waitcnt lgkmcnt(0)" ::: "memory"); \
        __builtin_amdgcn_s_barrier();                      \
    } while (0)
#define VM_WAIT(N) asm volatile("s_waitcnt vmcnt(" #N ")" ::: "memory")

__global__ __launch_bounds__(256, 4)
void disco_fused_kernel(const float* __restrict__ x,
                        const int*   __restrict__ hi_base,
                        float* __restrict__ out)
{
    // f32 staging, DMA-linear: item ii -> floats [ii*4, ii*4+4); 12 groups of 64
    __shared__ float xs_f[2][12 * 256];                        // 2*12288 B = 24576 B
    __shared__ __align__(16) unsigned short acc_s[WT][ACCP2];  // 9472 B  (34048 -> 4 blocks/CU)

    const int b    = blockIdx.x;        // 0..16199
    const int xcd  = b & (NXCD - 1);
    const int jb   = b >> 3;            // 0..2024
    const int h    = xcd * HBAND + jb / 45;
    const int tile = jb % 45;
    const int w0   = tile * WT;
    const int tid  = threadIdx.x;

    const int hib = hi_base[h];         // in [0, 716]

    // ---- zero acc_s k'-padding cols [260,288) ----
    #pragma unroll
    for (int t = 0; t < 2; ++t) {
        const int e = tid + t * 256;    // 0..511
        if (e < 16 * 28) acc_s[e / 28][260 + e % 28] = 0;
    }

    const int lane = tid & 63;
    const int wid  = tid >> 6;          // 4 waves
    const int n    = lane & 15;
    const int kg   = lane >> 4;

    // ---- load psi A-fragments, then drain vmcnt so it counts ONLY DMA ----
    bf16x8 afrag[3];
    #pragma unroll
    for (int ks = 0; ks < 3; ++ks)
        afrag[ks] = *(const bf16x8*)&g_pfrag[((h * 3 + ks) * 64 + lane) * 8];
    VM_WAIT(0);

    const int c0 = 2 * w0 - 4;          // in [-4, 1404], divisible by 4

    // chunk rd: rows = nc*9 (63 or 45), items = rows*10, padded to 768 (12 groups).
    // wave wid issues groups {wid, wid+4, wid+8} -> exactly 3 DMA loads per wave.
    #define ISSUE_DMA(RD, BUF, RMAX)                                             \
    do {                                                                         \
        const int cb = (RD) * CCH;                                               \
        _Pragma("unroll")                                                        \
        for (int it = 0; it < 3; ++it) {                                         \
            const int g64 = wid + 4 * it;                                        \
            const int ii  = g64 * 64 + lane;                                     \
            int row = ii / 10;                                                   \
            const int q = ii - row * 10;                                         \
            if (row > (RMAX)) row = (RMAX);                                      \
            const int dh = row % 9;                                              \
            const int c  = cb + row / 9;                                         \
            int r = hib + dh;                                                    \
            if (r > HIN_ - 1) r = HIN_ - 1;                                      \
            int gc = c0 + 4 * q;                                                 \
            if (gc < 0)          gc += WIN_;                                     \
            else if (gc >= WIN_) gc -= WIN_;                                     \
            gload_lds16(x + ((size_t)c * HIN_ + r) * WIN_ + gc,                  \
                        &xs_f[BUF][g64 * 256]);                                  \
        }                                                                        \
    } while (0)

    // prologue: chunk0 + chunk1 in flight; wait chunk0 (own 3 newest still fly)
    ISSUE_DMA(0, 0, 62);
    ISSUE_DMA(1, 1, 62);
    VM_WAIT(3);
    LDS_BARRIER();

    // ---- 4 rounds: phase-1 on buf[rd&1]; next-next chunk DMA issued after readers done ----
    #pragma unroll
    for (int rd = 0; rd < 4; ++rd) {
        const int nc = (rd == 3) ? (CIN_ - 3 * CCH) : CCH;   // 7,7,7,5
        const float* xsf = &xs_f[rd & 1][0];

        for (int cc = wid; cc < nc; cc += 4) {
            const int c = rd * CCH + cc;
            const float* rbase = xsf + (cc * 9) * XFP + 2 * n;
            f32x4 C = {0.f, 0.f, 0.f, 0.f};
            #pragma unroll
            for (int ks = 0; ks < 3; ++ks) {
                union { bf16x8 v; unsigned d[4]; unsigned short u[8]; } bf;
                if (ks < 2 || kg == 0) {
                    // pairs: dh = ks*4 + kg (uniform per 16-lane group)
                    const float* rp = rbase + (ks * 4 + kg) * XFP;
                    #pragma unroll
                    for (int t = 0; t < 4; ++t) {
                        const float2 v2 = *reinterpret_cast<const float2*>(rp + 2 * t);
                        bf.d[t] = pack_bf2(v2.x, v2.y);
                    }
                } else if (kg == 1) {
                    // singles s=72..79: dh = e, dw = 8
                    #pragma unroll
                    for (int e = 0; e < 8; ++e)
                        bf.u[e] = f2bf_rne(rbase[e * XFP + 8]);
                } else if (kg == 2) {
                    bf.d[0] = bf.d[1] = bf.d[2] = bf.d[3] = 0;
                    bf.u[0] = f2bf_rne(rbase[8 * XFP + 8]);   // s=80
                } else {
                    bf.d[0] = bf.d[1] = bf.d[2] = bf.d[3] = 0;
                }
                C = __builtin_amdgcn_mfma_f32_16x16x32_bf16(afrag[ks], bf.v, C, 0, 0, 0);
            }
            // C row m = kg*4 + r -> acc_s[n][c*10 + m], packed pair stores (4B aligned)
            if (kg < 2) {
                unsigned* ap = reinterpret_cast<unsigned*>(&acc_s[n][c * 10 + kg * 4]);
                ap[0] = pack_bf2(C[0], C[1]);
                ap[1] = pack_bf2(C[2], C[3]);
            } else if (kg == 2) {
                *reinterpret_cast<unsigned*>(&acc_s[n][c * 10 + 8]) = pack_bf2(C[0], 0.f);
            }
        }

        if (rd == 0) {
            LDS_BARRIER();              // all waves done reading buf0
            ISSUE_DMA(2, 0, 62);        // chunk2 -> buf0
            VM_WAIT(3);                 // own chunk1 landed (chunk2 still flying)
            LDS_BARRIER();              // everyone's chunk1 landed
        } else if (rd == 1) {
            LDS_BARRIER();
            ISSUE_DMA(3, 1, 44);        // chunk3 -> buf1 (5 c's -> clamp row 44)
            VM_WAIT(3);                 // chunk2 landed
            LDS_BARRIER();
        } else if (rd == 2) {
            LDS_BARRIER();
            VM_WAIT(0);                 // chunk3 landed
            LDS_BARRIER();
        }
    }
    #undef ISSUE_DMA

    // ---- prefetch phase-2's first weight fragments BEFORE the barrier ----
    // (no LDS dependency; raw barrier doesn't drain vmcnt, so the weight-L2
    //  latency hides under the barrier instead of heading phase-2)
    const unsigned short* wp = g_whi + ((size_t)(wid * 4) * NKS2 * 64 + lane) * 8;
    bf16x8 wc[4];
    #pragma unroll
    for (int i = 0; i < 4; ++i)
        wc[i] = *(const bf16x8*)(wp + (size_t)i * NKS2 * 512);

    LDS_BARRIER();                      // acc_s complete before phase-2

    // ---- phase 2: C[256x16] = W[256xK'] * acc[K'x16], weight software-pipelined ----
    f32x4 C0 = {0.f, 0.f, 0.f, 0.f};
    f32x4 C1 = C0, C2 = C0, C3 = C0;

    #pragma unroll
    for (int ks = 0; ks < NKS2; ++ks) {
        bf16x8 wn[4];
        if (ks + 1 < NKS2) {
            #pragma unroll
            for (int i = 0; i < 4; ++i)
                wn[i] = *(const bf16x8*)(wp + ((size_t)i * NKS2 + (ks + 1)) * 512);
        }
        const bf16x8 bhi = *(const bf16x8*)&acc_s[n][ks * 32 + kg * 8];
        C0 = __builtin_amdgcn_mfma_f32_16x16x32_bf16(wc[0], bhi, C0, 0, 0, 0);
        C1 = __builtin_amdgcn_mfma_f32_16x16x32_bf16(wc[1], bhi, C1, 0, 0, 0);
        C2 = __builtin_amdgcn_mfma_f32_16x16x32_bf16(wc[2], bhi, C2, 0, 0, 0);
        C3 = __builtin_amdgcn_mfma_f32_16x16x32_bf16(wc[3], bhi, C3, 0, 0, 0);
        if (ks + 1 < NKS2) {
            #pragma unroll
            for (int i = 0; i < 4; ++i) wc[i] = wn[i];
        }
    }

    // ---- epilogue: D layout col = lane&15, row = (lane>>4)*4 + reg ----
    #pragma unroll
    for (int i = 0; i < 4; ++i) {
        const f32x4 acc = (i == 0) ? C0 : (i == 1) ? C1 : (i == 2) ? C2 : C3;
        const int m0 = (wid * 4 + i) * 16 + kg * 4;
        #pragma unroll
        for (int r = 0; r < 4; ++r) {
            out[(size_t)(m0 + r) * (HOUT_ * WOUT_) + h * WOUT_ + w0 + n] = acc[r];
        }
    }
}

extern "C" void kernel_launch(void* const* d_in, const int* in_sizes, int n_in,
                              void* d_out, int out_size, void* d_ws, size_t ws_size,
                              hipStream_t stream)
{
    const float* x       = (const float*)d_in[0];
    const float* psi     = (const float*)d_in[1];
    const float* weight  = (const float*)d_in[2];
    const int*   hi_base = (const int*)d_in[3];
    float* out = (float*)d_out;

    hipLaunchKernelGGL(prep_kernel, dim3(NMT * NKS2 + HOUT_), dim3(64), 0, stream,
                       weight, psi);

    hipLaunchKernelGGL(disco_fused_kernel, dim3(45 * HOUT_), dim3(256), 0, stream,
                       x, hi_base, out);
}